// Round 1
// baseline (941.707 us; speedup 1.0000x reference)
//
#include <hip/hip_runtime.h>

// Laplacian pyramid loss, exploiting linearity: pyr(p) - pyr(t) = pyr(p - t).
// Per level: down = blur(cur)[::2,::2]  (5x5 binomial /256, reflect pad 2)
//            up   = blur(zeros.at[::2,::2].set(down*4))  == separable interp
//            loss += w_l * mean(|cur - up|)

__device__ __forceinline__ int reflect_i(int m, int S) {
    if (m < 0) m = -m;
    if (m >= S) m = 2 * S - 2 - m;
    return m;
}

__device__ __forceinline__ float block_reduce_sum_256(float v) {
    #pragma unroll
    for (int o = 32; o > 0; o >>= 1) v += __shfl_down(v, o, 64);
    __shared__ float s[4];
    int lane = threadIdx.x & 63;
    int w = threadIdx.x >> 6;
    if (lane == 0) s[w] = v;
    __syncthreads();
    float r = 0.f;
    if (threadIdx.x == 0) r = s[0] + s[1] + s[2] + s[3];
    return r;
}

// ---- downsample: out[y,x] = sum K[i]K[j] cur_r[2y+i-2, 2x+j-2] ----
// Level 0 reads cur = p - t on the fly.
__global__ void down0_kernel(const float* __restrict__ p, const float* __restrict__ t,
                             float* __restrict__ down, int S, int D, int total) {
    int idx = blockIdx.x * blockDim.x + threadIdx.x;
    if (idx >= total) return;
    int x = idx % D, y = (idx / D) % D, n = idx / (D * D);
    size_t base = (size_t)n * S * S;
    const float* pp = p + base;
    const float* tt = t + base;
    const float k[5] = {1.f/16, 4.f/16, 6.f/16, 4.f/16, 1.f/16};
    int ys[5], xs[5];
    #pragma unroll
    for (int i = 0; i < 5; i++) {
        ys[i] = reflect_i(2 * y + i - 2, S);
        xs[i] = reflect_i(2 * x + i - 2, S);
    }
    float acc = 0.f;
    #pragma unroll
    for (int i = 0; i < 5; i++) {
        size_t r = (size_t)ys[i] * S;
        float row = 0.f;
        #pragma unroll
        for (int j = 0; j < 5; j++) row += k[j] * (pp[r + xs[j]] - tt[r + xs[j]]);
        acc += k[i] * row;
    }
    down[idx] = acc;
}

__global__ void down_kernel(const float* __restrict__ cur,
                            float* __restrict__ down, int S, int D, int total) {
    int idx = blockIdx.x * blockDim.x + threadIdx.x;
    if (idx >= total) return;
    int x = idx % D, y = (idx / D) % D, n = idx / (D * D);
    const float* img = cur + (size_t)n * S * S;
    const float k[5] = {1.f/16, 4.f/16, 6.f/16, 4.f/16, 1.f/16};
    int ys[5], xs[5];
    #pragma unroll
    for (int i = 0; i < 5; i++) {
        ys[i] = reflect_i(2 * y + i - 2, S);
        xs[i] = reflect_i(2 * x + i - 2, S);
    }
    float acc = 0.f;
    #pragma unroll
    for (int i = 0; i < 5; i++) {
        const float* row = img + (size_t)ys[i] * S;
        float rs = 0.f;
        #pragma unroll
        for (int j = 0; j < 5; j++) rs += k[j] * row[xs[j]];
        acc += k[i] * rs;
    }
    down[idx] = acc;
}

// ---- laplacian + reduce: sum |cur - up| * scale, atomicAdd into out ----
// up from down (reflect in the upsampled Z-space, parity-preserving):
//   even y: rows {y/2-1, y/2, y/2+1} w {1,6,1}/8 ; odd y: rows {y/2, y/2+1} w {1,1}/2
//   a < 0 -> -a ; a >= D -> 2D-1-a
template <int LEVEL0>
__global__ void lap_kernel(const float* __restrict__ curp, const float* __restrict__ curt,
                           const float* __restrict__ down, float* __restrict__ out,
                           int S, int D, int total, float scale) {
    int idx = blockIdx.x * blockDim.x + threadIdx.x;
    float v = 0.f;
    if (idx < total) {
        int x = idx % S, y = (idx / S) % S, n = idx / (S * S);
        const float* dimg = down + (size_t)n * D * D;

        bool ey = ((y & 1) == 0);
        int yh = y >> 1;
        int ay0 = ey ? yh - 1 : yh;
        int ay1 = ey ? yh     : yh + 1;
        int ay2 = ey ? yh + 1 : yh + 1;
        float wy0 = ey ? 0.125f : 0.5f;
        float wy1 = ey ? 0.75f  : 0.5f;
        float wy2 = ey ? 0.125f : 0.0f;

        bool ex = ((x & 1) == 0);
        int xh = x >> 1;
        int ax0 = ex ? xh - 1 : xh;
        int ax1 = ex ? xh     : xh + 1;
        int ax2 = ex ? xh + 1 : xh + 1;
        float wx0 = ex ? 0.125f : 0.5f;
        float wx1 = ex ? 0.75f  : 0.5f;
        float wx2 = ex ? 0.125f : 0.0f;

        if (ay0 < 0) ay0 = -ay0;  if (ay0 >= D) ay0 = 2 * D - 1 - ay0;
        if (ay1 < 0) ay1 = -ay1;  if (ay1 >= D) ay1 = 2 * D - 1 - ay1;
        if (ay2 < 0) ay2 = -ay2;  if (ay2 >= D) ay2 = 2 * D - 1 - ay2;
        if (ax0 < 0) ax0 = -ax0;  if (ax0 >= D) ax0 = 2 * D - 1 - ax0;
        if (ax1 < 0) ax1 = -ax1;  if (ax1 >= D) ax1 = 2 * D - 1 - ax1;
        if (ax2 < 0) ax2 = -ax2;  if (ax2 >= D) ax2 = 2 * D - 1 - ax2;

        const float* r0 = dimg + (size_t)ay0 * D;
        const float* r1 = dimg + (size_t)ay1 * D;
        const float* r2 = dimg + (size_t)ay2 * D;
        float s0 = wx0 * r0[ax0] + wx1 * r0[ax1] + wx2 * r0[ax2];
        float s1 = wx0 * r1[ax0] + wx1 * r1[ax1] + wx2 * r1[ax2];
        float s2 = wx0 * r2[ax0] + wx1 * r2[ax1] + wx2 * r2[ax2];
        float up = wy0 * s0 + wy1 * s1 + wy2 * s2;

        float c;
        if (LEVEL0) c = curp[idx] - curt[idx];
        else        c = curp[idx];
        v = fabsf(c - up);
    }
    float bsum = block_reduce_sum_256(v);
    if (threadIdx.x == 0) atomicAdd(out, bsum * scale);
}

extern "C" void kernel_launch(void* const* d_in, const int* in_sizes, int n_in,
                              void* d_out, int out_size, void* d_ws, size_t ws_size,
                              hipStream_t stream) {
    const float* p = (const float*)d_in[0];
    const float* t = (const float*)d_in[1];
    float* out = (float*)d_out;
    float* ws = (float*)d_ws;

    hipMemsetAsync(d_out, 0, sizeof(float), stream);

    const int N = 48;  // 16 batch * 3 channels, depthwise
    const int S[5] = {512, 256, 128, 64, 32};
    const float wgt[5] = {1.f, 2.f, 4.f, 8.f, 16.f};

    size_t off[5];
    size_t o = 0;
    for (int l = 0; l < 5; l++) {
        off[l] = o;
        o += (size_t)N * (S[l] / 2) * (S[l] / 2);
    }

    for (int l = 0; l < 5; l++) {
        int s = S[l], d = s / 2;
        int totD = N * d * d;
        int totS = N * s * s;
        float* dn = ws + off[l];
        if (l == 0) {
            down0_kernel<<<(totD + 255) / 256, 256, 0, stream>>>(p, t, dn, s, d, totD);
        } else {
            down_kernel<<<(totD + 255) / 256, 256, 0, stream>>>(ws + off[l - 1], dn, s, d, totD);
        }
        float scale = wgt[l] / (float)totS;
        if (l == 0) {
            lap_kernel<1><<<(totS + 255) / 256, 256, 0, stream>>>(p, t, dn, out, s, d, totS, scale);
        } else {
            lap_kernel<0><<<(totS + 255) / 256, 256, 0, stream>>>(ws + off[l - 1], nullptr, dn, out, s, d, totS, scale);
        }
    }
}

// Round 2
// 307.946 us; speedup vs baseline: 3.0580x; 3.0580x over previous
//
#include <hip/hip_runtime.h>

// Laplacian pyramid loss via linearity: pyr(p) - pyr(t) = pyr(p - t).
// Per level l: down = blur(cur)[::2,::2]  (5x5 binomial /256, reflect pad 2)
//              up   = separable interp of down (weights sum to 1; x4 folded in)
//              loss += w_l * mean(|cur - up|)
// Round 2: grid-stride + 4 px/thread (float4), ONE atomic per block
// (round-1 was atomic-serialization bound: 49k same-address atomics = 625us).

__device__ __forceinline__ int reflect_i(int m, int S) {
    if (m < 0) m = -m;
    if (m >= S) m = 2 * S - 2 - m;
    return m;
}

__device__ __forceinline__ void block_atomic_sum(float v, float* out, float scale) {
    #pragma unroll
    for (int o = 32; o > 0; o >>= 1) v += __shfl_down(v, o, 64);
    __shared__ float s[4];
    int lane = threadIdx.x & 63;
    int w = threadIdx.x >> 6;
    if (lane == 0) s[w] = v;
    __syncthreads();
    if (threadIdx.x == 0) atomicAdd(out, (s[0] + s[1] + s[2] + s[3]) * scale);
}

// ---- downsample: down[y,x] = (1/256) sum Kr[i]Kc[j] cur_r[2y+i-2, 2x+j-2]
// 4 consecutive outputs per thread; L0 forms cur = p - t on the fly.
template <int L0>
__global__ void down_kernel(const float* __restrict__ a, const float* __restrict__ b,
                            float* __restrict__ down, int S, int D, int ngrp) {
    const int gpr = D >> 2;  // 4-wide groups per row
    const int stride = gridDim.x * blockDim.x;
    for (int g = blockIdx.x * blockDim.x + threadIdx.x; g < ngrp; g += stride) {
        int xg = g % gpr;
        int y  = (g / gpr) % D;
        int n  = g / (gpr * D);
        int x0 = xg << 2;
        size_t base = (size_t)n * S * S;

        int xs[11];
        #pragma unroll
        for (int j = 0; j < 11; j++) xs[j] = reflect_i(2 * x0 - 2 + j, S);

        const float kr[5] = {1.f, 4.f, 6.f, 4.f, 1.f};
        float acc0 = 0.f, acc1 = 0.f, acc2 = 0.f, acc3 = 0.f;
        #pragma unroll
        for (int i = 0; i < 5; i++) {
            int yy = reflect_i(2 * y + i - 2, S);
            const float* ra = a + base + (size_t)yy * S;
            const float* rb = b + base + (size_t)yy * S;  // unused unless L0
            float v[11];
            #pragma unroll
            for (int j = 0; j < 11; j++) {
                float t = ra[xs[j]];
                if (L0) t -= rb[xs[j]];
                v[j] = t;
            }
            float w = kr[i];
            acc0 += w * (v[0] + 4.f * v[1] + 6.f * v[2] + 4.f * v[3] + v[4]);
            acc1 += w * (v[2] + 4.f * v[3] + 6.f * v[4] + 4.f * v[5] + v[6]);
            acc2 += w * (v[4] + 4.f * v[5] + 6.f * v[6] + 4.f * v[7] + v[8]);
            acc3 += w * (v[6] + 4.f * v[7] + 6.f * v[8] + 4.f * v[9] + v[10]);
        }
        float4 o;
        o.x = acc0 * (1.f / 256.f);
        o.y = acc1 * (1.f / 256.f);
        o.z = acc2 * (1.f / 256.f);
        o.w = acc3 * (1.f / 256.f);
        *(float4*)(down + (size_t)n * D * D + (size_t)y * D + x0) = o;
    }
}

// ---- laplacian + reduce: sum w/numel * |cur - up|
// up (parity-preserving separable interp, validated round 1):
//   even coord: {h-1, h, h+1} w {1,6,1}/8 ; odd: {h, h+1} w {1,1}/2
//   half-space reflect: a<0 -> -a ; a>=D -> 2D-1-a
template <int L0>
__global__ void lap_kernel(const float* __restrict__ a, const float* __restrict__ b,
                           const float* __restrict__ down, float* __restrict__ out,
                           int S, int D, int ngrp, float scale) {
    const int gpr = S >> 2;
    const int stride = gridDim.x * blockDim.x;
    float sum = 0.f;
    for (int g = blockIdx.x * blockDim.x + threadIdx.x; g < ngrp; g += stride) {
        int xg = g % gpr;
        int y  = (g / gpr) % S;
        int n  = g / (gpr * S);
        int x0 = xg << 2;
        size_t idx = (size_t)n * S * S + (size_t)y * S + x0;

        float4 c = *(const float4*)(a + idx);
        if (L0) {
            float4 t = *(const float4*)(b + idx);
            c.x -= t.x; c.y -= t.y; c.z -= t.z; c.w -= t.w;
        }

        int yh = y >> 1;
        bool ey = ((y & 1) == 0);
        int ay0 = ey ? yh - 1 : yh;
        int ay1 = ey ? yh : yh + 1;
        int ay2 = ey ? yh + 1 : yh + 1;
        float wy0 = ey ? 0.125f : 0.5f;
        float wy1 = ey ? 0.75f  : 0.5f;
        float wy2 = ey ? 0.125f : 0.0f;
        if (ay0 < 0) ay0 = -ay0;
        if (ay1 >= D) ay1 = 2 * D - 1 - ay1;
        if (ay2 >= D) ay2 = 2 * D - 1 - ay2;

        int g2 = xg << 1;
        int d0 = g2 - 1, d1 = g2, d2 = g2 + 1, d3 = g2 + 2;
        if (d0 < 0) d0 = 1;
        if (d3 >= D) d3 = 2 * D - 1 - d3;

        const float* dimg = down + (size_t)n * D * D;
        float u0 = 0.f, u1 = 0.f, u2 = 0.f, u3 = 0.f;
        const int   ay[3] = {ay0, ay1, ay2};
        const float wy[3] = {wy0, wy1, wy2};
        #pragma unroll
        for (int r = 0; r < 3; r++) {
            const float* row = dimg + (size_t)ay[r] * D;
            float w0 = row[d0], w1 = row[d1], w2 = row[d2], w3 = row[d3];
            float wyr = wy[r];
            u0 += wyr * (w0 + 6.f * w1 + w2) * 0.125f;
            u1 += wyr * (w1 + w2) * 0.5f;
            u2 += wyr * (w1 + 6.f * w2 + w3) * 0.125f;
            u3 += wyr * (w2 + w3) * 0.5f;
        }
        sum += fabsf(c.x - u0) + fabsf(c.y - u1) + fabsf(c.z - u2) + fabsf(c.w - u3);
    }
    block_atomic_sum(sum, out, scale);
}

extern "C" void kernel_launch(void* const* d_in, const int* in_sizes, int n_in,
                              void* d_out, int out_size, void* d_ws, size_t ws_size,
                              hipStream_t stream) {
    const float* p = (const float*)d_in[0];
    const float* t = (const float*)d_in[1];
    float* out = (float*)d_out;
    float* ws = (float*)d_ws;

    hipMemsetAsync(d_out, 0, sizeof(float), stream);

    const int N = 48;  // 16 batch * 3 channels (depthwise)
    const int S[5] = {512, 256, 128, 64, 32};
    const float wgt[5] = {1.f, 2.f, 4.f, 8.f, 16.f};

    size_t off[5];
    size_t o = 0;
    for (int l = 0; l < 5; l++) {
        off[l] = o;
        o += (size_t)N * (S[l] / 2) * (S[l] / 2);
    }

    for (int l = 0; l < 5; l++) {
        int s = S[l], d = s / 2;
        int ngD = N * d * (d / 4);
        int ngS = N * s * (s / 4);
        float* dn = ws + off[l];
        int nbD = (ngD + 255) / 256; if (nbD > 2048) nbD = 2048;
        int nbS = (ngS + 255) / 256; if (nbS > 2048) nbS = 2048;
        if (l == 0) {
            down_kernel<1><<<nbD, 256, 0, stream>>>(p, t, dn, s, d, ngD);
        } else {
            down_kernel<0><<<nbD, 256, 0, stream>>>(ws + off[l - 1], nullptr, dn, s, d, ngD);
        }
        float scale = wgt[l] / (float)(N * s * s);
        if (l == 0) {
            lap_kernel<1><<<nbS, 256, 0, stream>>>(p, t, dn, out, s, d, ngS, scale);
        } else {
            lap_kernel<0><<<nbS, 256, 0, stream>>>(ws + off[l - 1], nullptr, dn, out, s, d, ngS, scale);
        }
    }
}

// Round 3
// 128.775 us; speedup vs baseline: 7.3128x; 2.3913x over previous
//
#include <hip/hip_runtime.h>

// Laplacian pyramid loss via linearity: pyr(p) - pyr(t) = pyr(p - t).
// Per level: down = blur(cur)[::2,::2]  (5x5 binomial /256, reflect pad 2)
//            up   = separable parity interp of down (x4 folded, weights sum 1)
//            loss += w_l * mean(|cur - up|)
// R3: vectorized float4 loads + per-thread tiles (down: 4x4 outputs with
// h-row reuse; lap: 8x2 px sharing 3 down rows). Border reflect handled by
// clamped vec-load base + static tap patches (no divergent scalar path).

__device__ __forceinline__ int reflect_i(int m, int S) {
    if (m < 0) m = -m;
    if (m >= S) m = 2 * S - 2 - m;
    return m;
}

__device__ __forceinline__ void block_atomic_sum(float v, float* out, float scale) {
    #pragma unroll
    for (int o = 32; o > 0; o >>= 1) v += __shfl_down(v, o, 64);
    __shared__ float s[4];
    int lane = threadIdx.x & 63;
    int w = threadIdx.x >> 6;
    if (lane == 0) s[w] = v;
    __syncthreads();
    if (threadIdx.x == 0) atomicAdd(out, (s[0] + s[1] + s[2] + s[3]) * scale);
}

// ---- down: thread computes 4x4 down outputs at (yd0..yd0+3, g0..g0+3).
// Per source row r (11 rows): 4 aligned float4 loads cover cols [2g0-4, 2g0+12),
// horizontal 5-tap at 4 positions -> h[r][0..3]; vertical 5-tap over h rows.
template <int L0>
__global__ void down_kernel(const float* __restrict__ a, const float* __restrict__ b,
                            float* __restrict__ down, int S, int D, int ngrp) {
    const int gpc = D >> 2;
    const int stride = gridDim.x * blockDim.x;
    for (int g = blockIdx.x * blockDim.x + threadIdx.x; g < ngrp; g += stride) {
        int xg = g % gpc;
        int yg = (g / gpc) % gpc;
        int n  = g / (gpc * gpc);
        int g0 = xg << 2;
        int yd0 = yg << 2;
        size_t base = (size_t)n * S * S;

        int sx0 = 2 * g0 - 4;
        int sx0c = sx0 < 0 ? 0 : (sx0 > S - 16 ? S - 16 : sx0);
        int edge = (g0 == 0) ? -1 : ((g0 == D - 4) ? 1 : 0);

        float h[11][4];
        #pragma unroll
        for (int r = 0; r < 11; r++) {
            int sy = reflect_i(2 * yd0 - 2 + r, S);
            const float* rowA = a + base + (size_t)sy * S + sx0c;
            float v[16];
            #pragma unroll
            for (int q = 0; q < 4; q++) {
                float4 t4 = *(const float4*)(rowA + 4 * q);
                v[4*q+0] = t4.x; v[4*q+1] = t4.y; v[4*q+2] = t4.z; v[4*q+3] = t4.w;
            }
            if (L0) {
                const float* rowB = b + base + (size_t)sy * S + sx0c;
                #pragma unroll
                for (int q = 0; q < 4; q++) {
                    float4 t4 = *(const float4*)(rowB + 4 * q);
                    v[4*q+0] -= t4.x; v[4*q+1] -= t4.y; v[4*q+2] -= t4.z; v[4*q+3] -= t4.w;
                }
            }
            if (edge == 0) {
                // v[o] = col sx0+o; col 2g0+2i-2+j -> o = 2i+2+j
                #pragma unroll
                for (int i = 0; i < 4; i++)
                    h[r][i] = v[2*i+2] + 4.f*v[2*i+3] + 6.f*v[2*i+4] + 4.f*v[2*i+5] + v[2*i+6];
            } else if (edge < 0) {
                // loaded from col 0; col -k reflects to k
                h[r][0] = 6.f*v[0] + 8.f*v[1] + 2.f*v[2];
                #pragma unroll
                for (int i = 1; i < 4; i++)
                    h[r][i] = v[2*i-2] + 4.f*v[2*i-1] + 6.f*v[2*i] + 4.f*v[2*i+1] + v[2*i+2];
            } else {
                // loaded from col S-16: col c -> v[c-(S-16)]; col S reflects to S-2 -> v[14]
                #pragma unroll
                for (int i = 0; i < 3; i++)
                    h[r][i] = v[2*i+6] + 4.f*v[2*i+7] + 6.f*v[2*i+8] + 4.f*v[2*i+9] + v[2*i+10];
                h[r][3] = v[12] + 4.f*v[13] + 7.f*v[14] + 4.f*v[15];
            }
        }

        float* drow = down + (size_t)n * D * D + (size_t)yd0 * D + g0;
        #pragma unroll
        for (int rr = 0; rr < 4; rr++) {
            float4 o4;
            o4.x = (h[2*rr][0] + 4.f*h[2*rr+1][0] + 6.f*h[2*rr+2][0] + 4.f*h[2*rr+3][0] + h[2*rr+4][0]) * (1.f/256.f);
            o4.y = (h[2*rr][1] + 4.f*h[2*rr+1][1] + 6.f*h[2*rr+2][1] + 4.f*h[2*rr+3][1] + h[2*rr+4][1]) * (1.f/256.f);
            o4.z = (h[2*rr][2] + 4.f*h[2*rr+1][2] + 6.f*h[2*rr+2][2] + 4.f*h[2*rr+3][2] + h[2*rr+4][2]) * (1.f/256.f);
            o4.w = (h[2*rr][3] + 4.f*h[2*rr+1][3] + 6.f*h[2*rr+2][3] + 4.f*h[2*rr+3][3] + h[2*rr+4][3]) * (1.f/256.f);
            *(float4*)(drow + (size_t)rr * D) = o4;
        }
    }
}

// ---- lap: thread handles 8 px x 2 rows (even row 2m, odd row 2m+1), which
// share down rows m-1, m, m+1. Horizontal interp from 3 float4 down loads.
// up weights (verified R1/R2): even coord {1,6,1}/8 on h-1,h,h+1; odd {1,1}/2.
template <int L0>
__global__ void lap_kernel(const float* __restrict__ a, const float* __restrict__ b,
                           const float* __restrict__ down, float* __restrict__ out,
                           int S, int D, int ngrp, float scale) {
    const int gpc = S >> 3;
    const int rows = S >> 1;
    const int stride = gridDim.x * blockDim.x;
    float sum = 0.f;
    for (int g = blockIdx.x * blockDim.x + threadIdx.x; g < ngrp; g += stride) {
        int xg = g % gpc;
        int m  = (g / gpc) % rows;
        int n  = g / (gpc * rows);
        int x0 = xg << 3;
        int gq = x0 >> 1;  // down col base, multiple of 4
        size_t base = (size_t)n * S * S;

        float c0[8], c1[8];
        {
            const float* r0p = a + base + (size_t)(2 * m) * S + x0;
            #pragma unroll
            for (int q = 0; q < 2; q++) {
                float4 t4 = *(const float4*)(r0p + 4 * q);
                c0[4*q+0] = t4.x; c0[4*q+1] = t4.y; c0[4*q+2] = t4.z; c0[4*q+3] = t4.w;
                float4 u4 = *(const float4*)(r0p + S + 4 * q);
                c1[4*q+0] = u4.x; c1[4*q+1] = u4.y; c1[4*q+2] = u4.z; c1[4*q+3] = u4.w;
            }
            if (L0) {
                const float* r0t = b + base + (size_t)(2 * m) * S + x0;
                #pragma unroll
                for (int q = 0; q < 2; q++) {
                    float4 t4 = *(const float4*)(r0t + 4 * q);
                    c0[4*q+0] -= t4.x; c0[4*q+1] -= t4.y; c0[4*q+2] -= t4.z; c0[4*q+3] -= t4.w;
                    float4 u4 = *(const float4*)(r0t + S + 4 * q);
                    c1[4*q+0] -= u4.x; c1[4*q+1] -= u4.y; c1[4*q+2] -= u4.z; c1[4*q+3] -= u4.w;
                }
            }
        }

        int ry0 = (m == 0) ? 1 : m - 1;
        int ry1 = m;
        int ry2 = (m + 1 >= D) ? (D - 1) : m + 1;
        const int ry[3] = {ry0, ry1, ry2};

        int bq = gq - 4;
        if (bq < 0) bq = 0;
        if (bq > D - 12) bq = D - 12;
        int edge = (gq == 0) ? -1 : ((gq == D - 4) ? 1 : 0);

        const float* dimg = down + (size_t)n * D * D;
        float hs[3][8];
        #pragma unroll
        for (int r = 0; r < 3; r++) {
            const float* row = dimg + (size_t)ry[r] * D + bq;
            float v[12];
            #pragma unroll
            for (int q = 0; q < 3; q++) {
                float4 t4 = *(const float4*)(row + 4 * q);
                v[4*q+0] = t4.x; v[4*q+1] = t4.y; v[4*q+2] = t4.z; v[4*q+3] = t4.w;
            }
            if (edge == 0) {
                #pragma unroll
                for (int c = 0; c < 8; c++) {
                    int o = (c >> 1) + 4;
                    hs[r][c] = (c & 1) ? 0.5f * (v[o] + v[o+1])
                                       : 0.125f * (v[o-1] + 6.f*v[o] + v[o+1]);
                }
            } else if (edge < 0) {
                // loaded from col 0; col -1 reflects to 1
                hs[r][0] = 0.125f * (6.f*v[0] + 2.f*v[1]);
                #pragma unroll
                for (int c = 1; c < 8; c++) {
                    int o = (c >> 1);
                    hs[r][c] = (c & 1) ? 0.5f * (v[o] + v[o+1])
                                       : 0.125f * (v[o-1] + 6.f*v[o] + v[o+1]);
                }
            } else {
                // loaded from col D-12; col D reflects to D-1 -> v[11]
                #pragma unroll
                for (int c = 0; c < 6; c++) {
                    int o = (c >> 1) + 8;
                    hs[r][c] = (c & 1) ? 0.5f * (v[o] + v[o+1])
                                       : 0.125f * (v[o-1] + 6.f*v[o] + v[o+1]);
                }
                hs[r][6] = 0.125f * (v[10] + 7.f*v[11]);
                hs[r][7] = v[11];
            }
        }

        #pragma unroll
        for (int c = 0; c < 8; c++) {
            float ue = 0.125f * (hs[0][c] + 6.f * hs[1][c] + hs[2][c]);
            float uo = 0.5f * (hs[1][c] + hs[2][c]);
            sum += fabsf(c0[c] - ue) + fabsf(c1[c] - uo);
        }
    }
    block_atomic_sum(sum, out, scale);
}

extern "C" void kernel_launch(void* const* d_in, const int* in_sizes, int n_in,
                              void* d_out, int out_size, void* d_ws, size_t ws_size,
                              hipStream_t stream) {
    const float* p = (const float*)d_in[0];
    const float* t = (const float*)d_in[1];
    float* out = (float*)d_out;
    float* ws = (float*)d_ws;

    hipMemsetAsync(d_out, 0, sizeof(float), stream);

    const int N = 48;  // 16 batch * 3 channels (depthwise)
    const int S[5] = {512, 256, 128, 64, 32};
    const float wgt[5] = {1.f, 2.f, 4.f, 8.f, 16.f};

    size_t off[5];
    size_t o = 0;
    for (int l = 0; l < 5; l++) {
        off[l] = o;
        o += (size_t)N * (S[l] / 2) * (S[l] / 2);
    }

    for (int l = 0; l < 5; l++) {
        int s = S[l], d = s / 2;
        int ngD = N * (d / 4) * (d / 4);
        int ngS = N * (s / 2) * (s / 8);
        float* dn = ws + off[l];
        int nbD = (ngD + 255) / 256; if (nbD > 2048) nbD = 2048;
        int nbS = (ngS + 255) / 256; if (nbS > 2048) nbS = 2048;
        if (l == 0) {
            down_kernel<1><<<nbD, 256, 0, stream>>>(p, t, dn, s, d, ngD);
        } else {
            down_kernel<0><<<nbD, 256, 0, stream>>>(ws + off[l - 1], nullptr, dn, s, d, ngD);
        }
        float scale = wgt[l] / (float)(N * s * s);
        if (l == 0) {
            lap_kernel<1><<<nbS, 256, 0, stream>>>(p, t, dn, out, s, d, ngS, scale);
        } else {
            lap_kernel<0><<<nbS, 256, 0, stream>>>(ws + off[l - 1], nullptr, dn, out, s, d, ngS, scale);
        }
    }
}

// Round 4
// 96.177 us; speedup vs baseline: 9.7914x; 1.3389x over previous
//
#include <hip/hip_runtime.h>

// Laplacian pyramid loss via linearity: pyr(p) - pyr(t) = pyr(p - t).
// R4: per-level FUSED kernel: stage cur tile (p-t or prev down) in LDS once,
// compute down tile + 1-halo in LDS (separable h then v), write interior down
// to global for the next level, then up + sum|cur-up| from LDS. p,t read ONCE.
// Symmetric 5-tap => halo down computed from reflect-patched cur equals the
// reflected down value, so phases 2-4 are edge-logic-free. Lap via 2x2 quads
// (no parity divergence). Block sums spread over 64 atomic slots.

__device__ __forceinline__ int reflect_i(int m, int S) {
    if (m < 0) m = -m;
    if (m >= S) m = 2 * S - 2 - m;
    return m;
}

// cur tile: rows ty0-4 .. ty0+TH+2  (RC = TH+7 rows)
//           cols tx0-8 .. tx0+TW+7  (WC = TW+16 cols, 16B aligned)
// down tile (with halo): rows yd0-1 .. yd0+TH/2, cols xd0-1 .. xd0+TW/2
template <int TW, int TH, int L0>
__global__ void fused_kernel(const float* __restrict__ a, const float* __restrict__ b,
                             float* __restrict__ dwn, float* __restrict__ acc,
                             int S, float scale) {
    const int D = S >> 1;
    const int nx = S / TW, ny = S / TH;
    const int RC = TH + 7;
    const int WC = TW + 16;
    const int CH = TW / 2 + 2;   // down/h cols incl halo
    const int RD = TH / 2 + 2;   // down rows incl halo
    const int HS = CH + 2;       // padded stride

    __shared__ float Lc[RC][WC];
    __shared__ float Lh[RC][HS];
    __shared__ float Ld[RD][HS];

    int bid = blockIdx.x;
    int bx = bid % nx;
    int by = (bid / nx) % ny;
    int n  = bid / (nx * ny);
    int tx0 = bx * TW, ty0 = by * TH;
    int xd0 = tx0 >> 1, yd0 = ty0 >> 1;
    size_t base = (size_t)n * S * S;
    int tid = threadIdx.x;

    // ---- phase 1: stage cur into LDS (vectorized, row-reflect via source row)
    const int C4 = WC / 4;
    for (int i = tid; i < RC * C4; i += 256) {
        int r = i / C4, q = i % C4;
        int gc = tx0 - 8 + 4 * q;
        if (gc < 0 || gc > S - 4) continue;   // OOB cols patched below
        int gy = reflect_i(ty0 - 4 + r, S);
        float4 v = *(const float4*)(a + base + (size_t)gy * S + gc);
        if constexpr (L0) {
            float4 u = *(const float4*)(b + base + (size_t)gy * S + gc);
            v.x -= u.x; v.y -= u.y; v.z -= u.z; v.w -= u.w;
        }
        *(float4*)&Lc[r][4 * q] = v;
    }
    __syncthreads();
    // column reflect patches (block-uniform conditions)
    if (tx0 == 0) {
        for (int i = tid; i < RC * 4; i += 256) {
            int r = i >> 2, j = i & 3;
            Lc[r][4 + j] = Lc[r][12 - j];          // cur col -4+j <- col 4-j
        }
    }
    if (tx0 + TW == S) {
        for (int i = tid; i < RC * 3; i += 256) {
            int r = i / 3, k = i % 3;
            Lc[r][TW + 8 + k] = Lc[r][TW + 6 - k]; // cur col S+k <- col S-2-k
        }
    }
    __syncthreads();

    // ---- phase 2: horizontal 5-tap at down col xd0-1+xh
    for (int i = tid; i < RC * CH; i += 256) {
        int r = i / CH, xh = i % CH;
        int c = 2 * xh + 4;
        Lh[r][xh] = Lc[r][c] + 4.f * Lc[r][c + 1] + 6.f * Lc[r][c + 2]
                  + 4.f * Lc[r][c + 3] + Lc[r][c + 4];
    }
    __syncthreads();

    // ---- phase 3: vertical 5-tap -> down tile (halo included)
    for (int i = tid; i < RD * CH; i += 256) {
        int yh = i / CH, xh = i % CH;
        int r = 2 * yh;
        Ld[yh][xh] = (Lh[r][xh] + 4.f * Lh[r + 1][xh] + 6.f * Lh[r + 2][xh]
                    + 4.f * Lh[r + 3][xh] + Lh[r + 4][xh]) * (1.f / 256.f);
    }
    __syncthreads();

    // ---- phase 3b: write interior down to global (input of next level)
    {
        size_t dbase = (size_t)n * D * D;
        const int CW4 = TW / 8;
        for (int i = tid; i < (TH / 2) * CW4; i += 256) {
            int rr = i / CW4, k = i % CW4;
            float4 o4;
            o4.x = Ld[1 + rr][1 + 4 * k];
            o4.y = Ld[1 + rr][2 + 4 * k];
            o4.z = Ld[1 + rr][3 + 4 * k];
            o4.w = Ld[1 + rr][4 + 4 * k];
            *(float4*)(dwn + dbase + (size_t)(yd0 + rr) * D + xd0 + 4 * k) = o4;
        }
    }

    // ---- phase 4: up + |cur - up| on 2x2 quads (shared 3x3 down taps)
    float sum = 0.f;
    for (int i = tid; i < (TH / 2) * (TW / 2); i += 256) {
        int yh2 = i / (TW / 2), q = i % (TW / 2);
        float A00 = Ld[yh2][q],     A01 = Ld[yh2][q + 1],     A02 = Ld[yh2][q + 2];
        float A10 = Ld[yh2 + 1][q], A11 = Ld[yh2 + 1][q + 1], A12 = Ld[yh2 + 1][q + 2];
        float A20 = Ld[yh2 + 2][q], A21 = Ld[yh2 + 2][q + 1], A22 = Ld[yh2 + 2][q + 2];
        float ex0 = (A00 + 6.f * A01 + A02) * 0.125f;
        float ex1 = (A10 + 6.f * A11 + A12) * 0.125f;
        float ex2 = (A20 + 6.f * A21 + A22) * 0.125f;
        float ox0 = (A01 + A02) * 0.5f;
        float ox1 = (A11 + A12) * 0.5f;
        float ox2 = (A21 + A22) * 0.5f;
        float uee = (ex0 + 6.f * ex1 + ex2) * 0.125f;
        float ueo = (ox0 + 6.f * ox1 + ox2) * 0.125f;
        float uoe = (ex1 + ex2) * 0.5f;
        float uoo = (ox1 + ox2) * 0.5f;
        int ry = 2 * yh2 + 4, cx = 2 * q + 8;
        sum += fabsf(Lc[ry][cx] - uee) + fabsf(Lc[ry][cx + 1] - ueo)
             + fabsf(Lc[ry + 1][cx] - uoe) + fabsf(Lc[ry + 1][cx + 1] - uoo);
    }

    // block reduce -> one atomic into a 64-way-spread slot
    #pragma unroll
    for (int o = 32; o > 0; o >>= 1) sum += __shfl_down(sum, o, 64);
    __shared__ float s[4];
    int lane = tid & 63, w = tid >> 6;
    if (lane == 0) s[w] = sum;
    __syncthreads();
    if (tid == 0) atomicAdd(&acc[bid & 63], (s[0] + s[1] + s[2] + s[3]) * scale);
}

__global__ void finish_kernel(const float* __restrict__ acc, float* __restrict__ out) {
    float v = acc[threadIdx.x];
    #pragma unroll
    for (int o = 32; o > 0; o >>= 1) v += __shfl_down(v, o, 64);
    if (threadIdx.x == 0) out[0] = v;
}

extern "C" void kernel_launch(void* const* d_in, const int* in_sizes, int n_in,
                              void* d_out, int out_size, void* d_ws, size_t ws_size,
                              hipStream_t stream) {
    const float* p = (const float*)d_in[0];
    const float* t = (const float*)d_in[1];
    float* out = (float*)d_out;
    float* acc = (float*)d_ws;          // 64 accumulator slots
    float* buf = acc + 64;              // down buffers

    hipMemsetAsync(acc, 0, 64 * sizeof(float), stream);

    const int N = 48;  // 16 batch * 3 channels (depthwise)
    const int S[5] = {512, 256, 128, 64, 32};
    const float wgt[5] = {1.f, 2.f, 4.f, 8.f, 16.f};

    size_t off[5];
    size_t o = 0;
    for (int l = 0; l < 5; l++) {
        off[l] = o;
        o += (size_t)N * (S[l] / 2) * (S[l] / 2);
    }

    for (int l = 0; l < 5; l++) {
        int s = S[l];
        float scale = wgt[l] / (float)(N * s * s);
        float* dn = buf + off[l];
        if (l == 0) {
            int nb = N * (s / 64) * (s / 32);
            fused_kernel<64, 32, 1><<<nb, 256, 0, stream>>>(p, t, dn, acc, s, scale);
        } else if (s >= 128) {
            int nb = N * (s / 64) * (s / 32);
            fused_kernel<64, 32, 0><<<nb, 256, 0, stream>>>(buf + off[l - 1], nullptr, dn, acc, s, scale);
        } else {
            int nb = N * (s / 32) * (s / 16);
            fused_kernel<32, 16, 0><<<nb, 256, 0, stream>>>(buf + off[l - 1], nullptr, dn, acc, s, scale);
        }
    }
    finish_kernel<<<1, 64, 0, stream>>>(acc, out);
}

// Round 5
// 82.465 us; speedup vs baseline: 11.4195x; 1.1663x over previous
//
#include <hip/hip_runtime.h>

// Laplacian pyramid loss via linearity: pyr(p) - pyr(t) = pyr(p - t).
// R5: R4's fused per-level kernel, restructured for memory-level parallelism:
// phase 1 issues ALL global loads into register arrays (static unroll) before
// any LDS write, and __launch_bounds__(256,2) lifts the VGPR cap (R4: VGPR=12
// -> 1 outstanding load/thread -> 2 TB/s). Levels 3+4 fused into one in-LDS
// pyramid kernel (48 blocks). Symmetric-tap halo trick from R4 retained.

__device__ __forceinline__ int reflect_i(int m, int S) {
    if (m < 0) m = -m;
    if (m >= S) m = 2 * S - 2 - m;
    return m;
}

// cur tile: rows ty0-4 .. ty0+TH+2  (RC = TH+7)
//           cols tx0-8 .. tx0+TW+7  (WC = TW+16, 16B aligned)
// down tile + halo: rows yd0-1 .. yd0+TH/2, cols xd0-1 .. xd0+TW/2
template <int TW, int TH, int L0>
__global__ __launch_bounds__(256, 2)
void fused_kernel(const float* __restrict__ a, const float* __restrict__ b,
                  float* __restrict__ dwn, float* __restrict__ acc,
                  int S, float scale) {
    const int D = S >> 1;
    const int nx = S / TW, ny = S / TH;
    constexpr int RC = TH + 7;
    constexpr int WC = TW + 16;
    constexpr int C4 = WC / 4;
    constexpr int CH = TW / 2 + 2;
    constexpr int RD = TH / 2 + 2;
    constexpr int HS = CH + 2;
    constexpr int TOT = RC * C4;
    constexpr int UN = (TOT + 255) / 256;

    __shared__ float Lc[RC][WC];
    __shared__ float Lh[RC][HS];
    __shared__ float Ld[RD][HS];

    int bid = blockIdx.x;
    int bx = bid % nx;
    int by = (bid / nx) % ny;
    int n  = bid / (nx * ny);
    int tx0 = bx * TW, ty0 = by * TH;
    int xd0 = tx0 >> 1, yd0 = ty0 >> 1;
    size_t base = (size_t)n * S * S;
    int tid = threadIdx.x;

    // ---- phase 1a: issue ALL global loads (register arrays, static unroll)
    float4 va[UN], vb[UN];
    bool ok[UN];
    #pragma unroll
    for (int u = 0; u < UN; u++) {
        int i = tid + 256 * u;
        int r = i / C4, q = i % C4;
        int gc = tx0 - 8 + 4 * q;
        ok[u] = (i < TOT) && (gc >= 0) && (gc <= S - 4);
        if (ok[u]) {
            int gy = reflect_i(ty0 - 4 + r, S);
            const float* src = a + base + (size_t)gy * S + gc;
            va[u] = *(const float4*)src;
            if constexpr (L0) vb[u] = *(const float4*)(b + base + (size_t)gy * S + gc);
        }
    }
    // ---- phase 1b: write to LDS
    #pragma unroll
    for (int u = 0; u < UN; u++) {
        if (ok[u]) {
            int i = tid + 256 * u;
            int r = i / C4, q = i % C4;
            float4 v = va[u];
            if constexpr (L0) {
                v.x -= vb[u].x; v.y -= vb[u].y; v.z -= vb[u].z; v.w -= vb[u].w;
            }
            *(float4*)&Lc[r][4 * q] = v;
        }
    }
    __syncthreads();
    // column reflect patches (block-uniform conditions)
    if (tx0 == 0) {
        for (int i = tid; i < RC * 4; i += 256) {
            int r = i >> 2, j = i & 3;
            Lc[r][4 + j] = Lc[r][12 - j];          // col -4+j <- col 4-j
        }
    }
    if (tx0 + TW == S) {
        for (int i = tid; i < RC * 3; i += 256) {
            int r = i / 3, k = i % 3;
            Lc[r][TW + 8 + k] = Lc[r][TW + 6 - k]; // col S+k <- col S-2-k
        }
    }
    if (tx0 == 0 || tx0 + TW == S) __syncthreads();

    // ---- phase 2: horizontal 5-tap at down col xd0-1+xh
    for (int i = tid; i < RC * CH; i += 256) {
        int r = i / CH, xh = i % CH;
        int c = 2 * xh + 4;
        Lh[r][xh] = Lc[r][c] + 4.f * Lc[r][c + 1] + 6.f * Lc[r][c + 2]
                  + 4.f * Lc[r][c + 3] + Lc[r][c + 4];
    }
    __syncthreads();

    // ---- phase 3: vertical 5-tap -> down tile (halo included)
    for (int i = tid; i < RD * CH; i += 256) {
        int yh = i / CH, xh = i % CH;
        int r = 2 * yh;
        Ld[yh][xh] = (Lh[r][xh] + 4.f * Lh[r + 1][xh] + 6.f * Lh[r + 2][xh]
                    + 4.f * Lh[r + 3][xh] + Lh[r + 4][xh]) * (1.f / 256.f);
    }
    __syncthreads();

    // ---- phase 3b: write interior down to global (next level's input)
    {
        size_t dbase = (size_t)n * D * D;
        constexpr int CW4 = TW / 8;
        for (int i = tid; i < (TH / 2) * CW4; i += 256) {
            int rr = i / CW4, k = i % CW4;
            float4 o4;
            o4.x = Ld[1 + rr][1 + 4 * k];
            o4.y = Ld[1 + rr][2 + 4 * k];
            o4.z = Ld[1 + rr][3 + 4 * k];
            o4.w = Ld[1 + rr][4 + 4 * k];
            *(float4*)(dwn + dbase + (size_t)(yd0 + rr) * D + xd0 + 4 * k) = o4;
        }
    }

    // ---- phase 4: up + |cur - up| on 2x2 quads (shared 3x3 down taps)
    float sum = 0.f;
    for (int i = tid; i < (TH / 2) * (TW / 2); i += 256) {
        int yh2 = i / (TW / 2), q = i % (TW / 2);
        float A00 = Ld[yh2][q],     A01 = Ld[yh2][q + 1],     A02 = Ld[yh2][q + 2];
        float A10 = Ld[yh2 + 1][q], A11 = Ld[yh2 + 1][q + 1], A12 = Ld[yh2 + 1][q + 2];
        float A20 = Ld[yh2 + 2][q], A21 = Ld[yh2 + 2][q + 1], A22 = Ld[yh2 + 2][q + 2];
        float ex0 = (A00 + 6.f * A01 + A02) * 0.125f;
        float ex1 = (A10 + 6.f * A11 + A12) * 0.125f;
        float ex2 = (A20 + 6.f * A21 + A22) * 0.125f;
        float ox0 = (A01 + A02) * 0.5f;
        float ox1 = (A11 + A12) * 0.5f;
        float ox2 = (A21 + A22) * 0.5f;
        float uee = (ex0 + 6.f * ex1 + ex2) * 0.125f;
        float ueo = (ox0 + 6.f * ox1 + ox2) * 0.125f;
        float uoe = (ex1 + ex2) * 0.5f;
        float uoo = (ox1 + ox2) * 0.5f;
        int ry = 2 * yh2 + 4, cx = 2 * q + 8;
        sum += fabsf(Lc[ry][cx] - uee) + fabsf(Lc[ry][cx + 1] - ueo)
             + fabsf(Lc[ry + 1][cx] - uoe) + fabsf(Lc[ry + 1][cx + 1] - uoo);
    }

    #pragma unroll
    for (int o = 32; o > 0; o >>= 1) sum += __shfl_down(sum, o, 64);
    __shared__ float s[4];
    int lane = tid & 63, w = tid >> 6;
    if (lane == 0) s[w] = sum;
    __syncthreads();
    if (tid == 0) atomicAdd(&acc[bid & 63], (s[0] + s[1] + s[2] + s[3]) * scale);
}

// ---- in-LDS level: cur (SxS, resident) -> dn (DxD), returns per-thread
// partial sum of |cur - up(dn)|. Reflect = plain index math (full image here).
__device__ float level_in_lds(const float* cur, float* h, float* dn, int S, int tid) {
    const int D = S >> 1;
    for (int i = tid; i < S * D; i += 256) {
        int r = i / D, xh = i % D;
        int c0 = reflect_i(2 * xh - 2, S), c1 = reflect_i(2 * xh - 1, S);
        int c3 = 2 * xh + 1, c4 = reflect_i(2 * xh + 2, S);
        const float* row = cur + r * S;
        h[i] = row[c0] + 4.f * row[c1] + 6.f * row[2 * xh] + 4.f * row[c3] + row[c4];
    }
    __syncthreads();
    for (int i = tid; i < D * D; i += 256) {
        int yh = i / D, xh = i % D;
        int r0 = reflect_i(2 * yh - 2, S), r1 = reflect_i(2 * yh - 1, S);
        int r3 = 2 * yh + 1, r4 = reflect_i(2 * yh + 2, S);
        dn[i] = (h[r0 * D + xh] + 4.f * h[r1 * D + xh] + 6.f * h[2 * yh * D + xh]
               + 4.f * h[r3 * D + xh] + h[r4 * D + xh]) * (1.f / 256.f);
    }
    __syncthreads();
    float sum = 0.f;
    for (int i = tid; i < D * D; i += 256) {
        int yh2 = i / D, q = i % D;
        int rm = (yh2 == 0) ? 1 : yh2 - 1;
        int rp = (yh2 == D - 1) ? D - 1 : yh2 + 1;
        int cm = (q == 0) ? 1 : q - 1;
        int cp = (q == D - 1) ? D - 1 : q + 1;
        float A00 = dn[rm * D + cm], A01 = dn[rm * D + q], A02 = dn[rm * D + cp];
        float A10 = dn[yh2 * D + cm], A11 = dn[yh2 * D + q], A12 = dn[yh2 * D + cp];
        float A20 = dn[rp * D + cm], A21 = dn[rp * D + q], A22 = dn[rp * D + cp];
        float ex0 = (A00 + 6.f * A01 + A02) * 0.125f;
        float ex1 = (A10 + 6.f * A11 + A12) * 0.125f;
        float ex2 = (A20 + 6.f * A21 + A22) * 0.125f;
        float ox0 = (A01 + A02) * 0.5f;
        float ox1 = (A11 + A12) * 0.5f;
        float ox2 = (A21 + A22) * 0.5f;
        float uee = (ex0 + 6.f * ex1 + ex2) * 0.125f;
        float ueo = (ox0 + 6.f * ox1 + ox2) * 0.125f;
        float uoe = (ex1 + ex2) * 0.5f;
        float uoo = (ox1 + ox2) * 0.5f;
        const float* c0 = cur + (2 * yh2) * S + 2 * q;
        sum += fabsf(c0[0] - uee) + fabsf(c0[1] - ueo)
             + fabsf(c0[S] - uoe) + fabsf(c0[S + 1] - uoo);
    }
    __syncthreads();
    return sum;
}

// levels 3+4 for one image per block: down2 (64x64) resident in LDS.
__global__ __launch_bounds__(256, 2)
void tail_kernel(const float* __restrict__ d2, float* __restrict__ acc,
                 float s3, float s4) {
    __shared__ float cur[64 * 64];
    __shared__ float h3[64 * 32];
    __shared__ float dn3[32 * 32];
    __shared__ float h4[32 * 16];
    __shared__ float dn4[16 * 16];
    int n = blockIdx.x, tid = threadIdx.x;
    const float4* src = (const float4*)(d2 + (size_t)n * 64 * 64);
    for (int i = tid; i < 64 * 16; i += 256) ((float4*)cur)[i] = src[i];
    __syncthreads();
    float sum = level_in_lds(cur, h3, dn3, 64, tid) * s3;
    sum += level_in_lds(dn3, h4, dn4, 32, tid) * s4;
    #pragma unroll
    for (int o = 32; o > 0; o >>= 1) sum += __shfl_down(sum, o, 64);
    __shared__ float s[4];
    int lane = tid & 63, w = tid >> 6;
    if (lane == 0) s[w] = sum;
    __syncthreads();
    if (tid == 0) atomicAdd(&acc[blockIdx.x & 63], s[0] + s[1] + s[2] + s[3]);
}

__global__ void finish_kernel(const float* __restrict__ acc, float* __restrict__ out) {
    float v = acc[threadIdx.x];
    #pragma unroll
    for (int o = 32; o > 0; o >>= 1) v += __shfl_down(v, o, 64);
    if (threadIdx.x == 0) out[0] = v;
}

extern "C" void kernel_launch(void* const* d_in, const int* in_sizes, int n_in,
                              void* d_out, int out_size, void* d_ws, size_t ws_size,
                              hipStream_t stream) {
    const float* p = (const float*)d_in[0];
    const float* t = (const float*)d_in[1];
    float* out = (float*)d_out;
    float* acc = (float*)d_ws;          // 64 accumulator slots
    float* buf = acc + 64;              // down buffers

    hipMemsetAsync(acc, 0, 64 * sizeof(float), stream);

    const int N = 48;  // 16 batch * 3 channels (depthwise)
    const int S[5] = {512, 256, 128, 64, 32};
    const float wgt[5] = {1.f, 2.f, 4.f, 8.f, 16.f};

    size_t off[5];
    size_t o = 0;
    for (int l = 0; l < 5; l++) {
        off[l] = o;
        o += (size_t)N * (S[l] / 2) * (S[l] / 2);
    }

    // levels 0-2: fused tile kernels
    for (int l = 0; l < 3; l++) {
        int s = S[l];
        float scale = wgt[l] / (float)(N * s * s);
        float* dn = buf + off[l];
        int nb = N * (s / 64) * (s / 32);
        if (l == 0) {
            fused_kernel<64, 32, 1><<<nb, 256, 0, stream>>>(p, t, dn, acc, s, scale);
        } else {
            fused_kernel<64, 32, 0><<<nb, 256, 0, stream>>>(buf + off[l - 1], nullptr, dn, acc, s, scale);
        }
    }
    // levels 3+4: whole sub-pyramid in LDS, one block per image
    tail_kernel<<<N, 256, 0, stream>>>(buf + off[2], acc,
                                       wgt[3] / (float)(N * 64 * 64),
                                       wgt[4] / (float)(N * 32 * 32));
    finish_kernel<<<1, 64, 0, stream>>>(acc, out);
}